// Round 3
// baseline (138.965 us; speedup 1.0000x reference)
//
#include <hip/hip_runtime.h>
#include <math.h>

#define EMBED  128
#define NUM_C  64
#define EPS    1e-5f
#define LDSROW 132          // 128 + 4 pad: spread b128 row reads stay bank-balanced
#define NPB    32           // nodes per block
#define NPW    8            // nodes per wave (4 waves/block)

__global__ __launch_bounds__(256, 4) void cd_main(
    const float* __restrict__ node_repr,   // [N,128]
    const float* __restrict__ mask,        // [N,1]
    const float* __restrict__ cent,        // [64,128]
    float* __restrict__ out,               // [64 + N*64]
    float* __restrict__ colsum,            // [nb*64] partials (or acc[64] atomic mode)
    float* __restrict__ msum,              // [nb] mask partials (or &acc[64])
    int N, int atomicMode)
{
    __shared__ float sc[NUM_C * LDSROW];   // 33792 B centroids (padded)
    __shared__ float wacc[4 * NUM_C];
    __shared__ float wmask[4];

    const int tid       = threadIdx.x;
    const int node_base = blockIdx.x * NPB;

    // Stage centroids -> LDS: 2048 coalesced float4
    for (int f = tid; f < NUM_C * EMBED / 4; f += 256) {
        const int c = f >> 5, e4 = f & 31;
        float4 v = ((const float4*)cent)[f];
        *(float4*)&sc[c * LDSROW + e4 * 4] = v;
    }
    __syncthreads();

    const int lane = tid & 63;             // = centroid index
    // Force wave id into an SGPR so all node addresses are provably uniform
    const int wave = __builtin_amdgcn_readfirstlane(tid >> 6);
    const int n0   = node_base + wave * NPW;   // uniform first node of this wave

    // sv = ||centroid_lane||^2 (bank-balanced spread reads)
    float sv = 0.f;
    #pragma unroll
    for (int e = 0; e < EMBED; e += 4) {
        float4 c4 = *(const float4*)&sc[lane * LDSROW + e];
        sv = fmaf(c4.x, c4.x, fmaf(c4.y, c4.y, fmaf(c4.z, c4.z, fmaf(c4.w, c4.w, sv))));
    }

    // Uniform (SGPR) row pointers + mask values, clamped for tail safety
    const float* rp[NPW];
    float mk[NPW];
    #pragma unroll
    for (int j = 0; j < NPW; ++j) {
        int nu = n0 + j;
        nu = nu < N ? nu : N - 1;
        rp[j] = node_repr + (long)nu * EMBED;
        mk[j] = mask[nu];                       // uniform scalar load
    }

    float su[NPW], dot[NPW];

    // su[j] = ||u_j||^2 : one coalesced float2/lane + wave shuffle reduce
    #pragma unroll
    for (int j = 0; j < NPW; ++j) {
        float2 u2 = *(const float2*)(rp[j] + lane * 2);
        float s = fmaf(u2.x, u2.x, u2.y * u2.y);
        #pragma unroll
        for (int k = 32; k; k >>= 1) s += __shfl_xor(s, k, 64);
        su[j]  = s;
        dot[j] = 0.f;
    }

    // Main loop: 1 spread ds_read_b128 (centroids, VGPR) +
    //            8 uniform s_load_dwordx4 (nodes, SGPR) + 32 v_fmac (SGPR src0)
    #pragma unroll 4
    for (int e = 0; e < EMBED; e += 4) {
        float4 c4 = *(const float4*)&sc[lane * LDSROW + e];
        #pragma unroll
        for (int j = 0; j < NPW; ++j) {
            float4 u4 = *(const float4*)(rp[j] + e);
            dot[j] = fmaf(u4.x, c4.x, fmaf(u4.y, c4.y,
                     fmaf(u4.z, c4.z, fmaf(u4.w, c4.w, dot[j]))));
        }
    }

    // Epilogue: distance, masked store (coalesced 256B/wave), per-wave column sums
    float gacc = 0.f;
    #pragma unroll
    for (int j = 0; j < NPW; ++j) {
        int n = n0 + j;
        float sq    = fmaxf(su[j] + sv - 2.f * dot[j], 0.f);
        float denom = fmaxf((1.f - su[j]) * (1.f - sv), EPS);
        float t     = fmaxf(2.f * sq / denom, EPS);
        float dist  = log1pf(t + sqrtf(t * (t + 2.f)));   // arccosh(1+t), stable
        float v     = dist * mk[j];
        if (n < N) {
            out[NUM_C + (long)n * NUM_C + lane] = v;
            gacc += v;
        }
    }

    wacc[(tid >> 6) * NUM_C + lane] = gacc;
    if (lane == 0) {
        float ms = 0.f;
        #pragma unroll
        for (int j = 0; j < NPW; ++j)
            if (n0 + j < N) ms += mk[j];
        wmask[tid >> 6] = ms;
    }
    __syncthreads();

    if (tid < NUM_C) {
        float s = wacc[tid] + wacc[NUM_C + tid] + wacc[2 * NUM_C + tid] + wacc[3 * NUM_C + tid];
        if (atomicMode) {
            atomicAdd(&colsum[tid], s);
            if (tid == 0)
                atomicAdd(&msum[0], wmask[0] + wmask[1] + wmask[2] + wmask[3]);
        } else {
            colsum[(long)blockIdx.x * NUM_C + tid] = s;
            if (tid == 0)
                msum[blockIdx.x] = wmask[0] + wmask[1] + wmask[2] + wmask[3];
        }
    }
}

// Reduce per-block partials -> out[0..63]
__global__ __launch_bounds__(256) void cd_fin(
    const float* __restrict__ colsum, const float* __restrict__ msum,
    float* __restrict__ out, int nb)
{
    __shared__ float red[256];
    __shared__ float mtot_s;
    const int tid = threadIdx.x;

    float m = 0.f;
    for (int b = tid; b < nb; b += 256) m += msum[b];
    #pragma unroll
    for (int k = 32; k; k >>= 1) m += __shfl_xor(m, k, 64);
    if ((tid & 63) == 0) red[tid >> 6] = m;
    __syncthreads();
    if (tid == 0) mtot_s = red[0] + red[1] + red[2] + red[3];
    __syncthreads();

    const int c = tid & 63, q = tid >> 6;
    float s = 0.f;
    for (int b = q; b < nb; b += 4) s += colsum[(long)b * NUM_C + c];
    red[tid] = s;
    __syncthreads();
    if (q == 0)
        out[c] = (red[c] + red[64 + c] + red[128 + c] + red[192 + c]) / mtot_s;
}

// atomic-mode fallback helpers
__global__ void cd_zero(float* acc) { if (threadIdx.x < NUM_C + 1) acc[threadIdx.x] = 0.f; }
__global__ void cd_fin_atomic(const float* __restrict__ acc, float* __restrict__ out) {
    int c = threadIdx.x;
    if (c < NUM_C) out[c] = acc[c] / acc[NUM_C];
}

extern "C" void kernel_launch(void* const* d_in, const int* in_sizes, int n_in,
                              void* d_out, int out_size, void* d_ws, size_t ws_size,
                              hipStream_t stream) {
    const float* node_repr = (const float*)d_in[0];
    const float* mask      = (const float*)d_in[1];
    const float* cent      = (const float*)d_in[2];
    float* out = (float*)d_out;

    const int N  = in_sizes[0] / EMBED;
    const int nb = (N + NPB - 1) / NPB;
    const size_t needed = (size_t)nb * NUM_C * sizeof(float) + (size_t)nb * sizeof(float);

    if (ws_size >= needed) {
        float* colsum = (float*)d_ws;
        float* msum   = colsum + (size_t)nb * NUM_C;
        cd_main<<<nb, 256, 0, stream>>>(node_repr, mask, cent, out, colsum, msum, N, 0);
        cd_fin<<<1, 256, 0, stream>>>(colsum, msum, out, nb);
    } else {
        float* acc = (float*)d_ws;   // 65 floats
        cd_zero<<<1, 128, 0, stream>>>(acc);
        cd_main<<<nb, 256, 0, stream>>>(node_repr, mask, cent, out, acc, acc + NUM_C, N, 1);
        cd_fin_atomic<<<1, 64, 0, stream>>>(acc, out);
    }
}